// Round 2
// baseline (431.588 us; speedup 1.0000x reference)
//
#include <hip/hip_runtime.h>
#include <hip/hip_bf16.h>

#define LRELU(v) ((v) > 0.0f ? (v) : 0.01f * (v))
#define EPS 0.1f

#define BSHIFT  9           // 512-node buckets -> NB ~391 blocks (~1.5/CU)
#define BSIZE   512
#define BIN_EPB 2048        // edges per k_bin block
#define BIN_CAP 6144        // bucket capacity (expected ~4092, wide headroom)

typedef __attribute__((ext_vector_type(8))) short bf16x8;
typedef __attribute__((ext_vector_type(4))) float f32x4;

// fast tanh via v_exp_f32 + v_rcp_f32: ~1e-7 abs err, saturates correctly
__device__ __forceinline__ float fast_tanh(float v)
{
    float e = __expf(2.0f * v);
    return 1.0f - 2.0f * __builtin_amdgcn_rcpf(e + 1.0f);
}

__device__ __forceinline__ float bf2f(unsigned short h)
{
    return __uint_as_float(((unsigned int)h) << 16);
}
__device__ __forceinline__ unsigned short f2bf(float f)
{
    unsigned int u = __float_as_uint(f);
    u += 0x7FFFu + ((u >> 16) & 1u);
    return (unsigned short)(u >> 16);
}

// ---------------------------------------------------------------------------
// K0: pack weights into bf16 MFMA B-fragment order (verified r15/r16).
// ---------------------------------------------------------------------------
__global__ void k_prep(const float* __restrict__ W_num, const float* __restrict__ W_cat,
                       const float* __restrict__ W_tog,
                       unsigned short* __restrict__ Wb, unsigned short* __restrict__ Wb1)
{
    int t = threadIdx.x;            // one block, 256 threads
    for (int i = t; i < 8 * 512; i += 256) {
        int tile = i >> 9;          // kt*4+nt
        int kt   = tile >> 2, nt = tile & 3;
        int lane = (i >> 3) & 63;
        int j    = i & 7;
        int k    = kt * 32 + (lane >> 4) * 8 + j;
        int n    = nt * 16 + (lane & 15);
        Wb[i] = f2bf(W_tog[k * 64 + n]);
    }
    for (int i = t; i < 4 * 512; i += 256) {
        int nt   = i >> 9;
        int lane = (i >> 3) & 63;
        int j    = i & 7;
        int k    = (lane >> 4) * 8 + j;     // 0..31
        int n    = nt * 16 + (lane & 15);   // 0..63
        float w;
        if (n < 32) w = (k < 20)  ? W_num[k * 32 + n]              : 0.0f;
        else        w = (k >= 20) ? W_cat[(k - 20) * 32 + (n - 32)] : 0.0f;
        Wb1[i] = f2bf(w);
    }
}

// ---------------------------------------------------------------------------
// K1: all-MFMA feature MLP, block = 64 nodes (r16-verified).
// ---------------------------------------------------------------------------
__global__ void __launch_bounds__(256)
k_feat(const float* __restrict__ num_prop,
       const float* __restrict__ cat_prop,
       const unsigned short* __restrict__ Wb1,
       const float* __restrict__ b_num, const float* __restrict__ b_cat,
       const unsigned short* __restrict__ Wb, const float* __restrict__ b_tog,
       const float* __restrict__ att_l, const float* __restrict__ att_r,
       unsigned short* __restrict__ xb,
       float* __restrict__ al, float* __restrict__ ar, int N)
{
    __shared__ unsigned short in_lds[64][40];   // bf16 inputs (32 used), pad 8
    __shared__ unsigned short mid[64][72];      // bf16 mid, pad 8

    int tid  = threadIdx.x;
    int lane = tid & 63;
    int w    = tid >> 6;                        // wave 0..3
    int blockStart = blockIdx.x * 64;

    for (int i = tid; i < 64 * 20; i += 256) {
        int node = i / 20, k = i % 20;
        int n = min(blockStart + node, N - 1);
        in_lds[node][k] = f2bf(num_prop[(size_t)n * 20 + k]);
    }
    for (int i = tid; i < 64 * 12; i += 256) {
        int node = i / 12, k = i % 12;
        int n = min(blockStart + node, N - 1);
        in_lds[node][20 + k] = f2bf(cat_prop[(size_t)n * 12 + k]);
    }
    __syncthreads();

    int q   = lane >> 4;
    int c16 = lane & 15;

    bf16x8 ain = *(const bf16x8*)&in_lds[w * 16 + c16][q * 8];
    #pragma unroll
    for (int nt = 0; nt < 4; nt++) {
        bf16x8 b = *(const bf16x8*)&Wb1[nt * 512 + lane * 8];
        f32x4 acc = {0.0f, 0.0f, 0.0f, 0.0f};
        acc = __builtin_amdgcn_mfma_f32_16x16x32_bf16(ain, b, acc, 0, 0, 0);
        int   ch   = nt * 16 + c16;
        float bias = (ch < 32) ? b_num[ch] : b_cat[ch - 32];
        #pragma unroll
        for (int r = 0; r < 4; r++) {
            float s = acc[r] + bias;
            s = LRELU(s);
            mid[w * 16 + q * 4 + r][ch] = f2bf(s);
        }
    }

    bf16x8 a0 = *(const bf16x8*)&mid[w * 16 + c16][q * 8];
    bf16x8 a1 = *(const bf16x8*)&mid[w * 16 + c16][32 + q * 8];

    float pal[4] = {0, 0, 0, 0};
    float par[4] = {0, 0, 0, 0};

    #pragma unroll
    for (int nt = 0; nt < 4; nt++) {
        bf16x8 b0 = *(const bf16x8*)&Wb[(0 * 4 + nt) * 512 + lane * 8];
        bf16x8 b1 = *(const bf16x8*)&Wb[(1 * 4 + nt) * 512 + lane * 8];
        f32x4 acc = {0.0f, 0.0f, 0.0f, 0.0f};
        acc = __builtin_amdgcn_mfma_f32_16x16x32_bf16(a0, b0, acc, 0, 0, 0);
        acc = __builtin_amdgcn_mfma_f32_16x16x32_bf16(a1, b1, acc, 0, 0, 0);

        int   ch  = nt * 16 + c16;
        float bt  = b_tog[ch];
        float atl = att_l[ch];
        float atr = att_r[ch];
        #pragma unroll
        for (int r = 0; r < 4; r++) {
            float s = acc[r] + bt;
            s = LRELU(s);
            int n = blockStart + w * 16 + q * 4 + r;
            if (n < N) xb[(size_t)n * 64 + ch] = f2bf(s);
            pal[r] = fmaf(s, atl, pal[r]);
            par[r] = fmaf(s, atr, par[r]);
        }
    }

    #pragma unroll
    for (int r = 0; r < 4; r++) {
        float pl = pal[r], pr = par[r];
        #pragma unroll
        for (int off = 8; off > 0; off >>= 1) {
            pl += __shfl_xor(pl, off);
            pr += __shfl_xor(pr, off);
        }
        int n = blockStart + w * 16 + q * 4 + r;
        if (c16 == 0 && n < N) { al[n] = pl; ar[n] = pr; }
    }
}

// ---------------------------------------------------------------------------
// K2: radix partition phase 1 (512 threads x 4 edges; no global atomics).
// ---------------------------------------------------------------------------
__global__ void k_bin(const int* __restrict__ src, const int* __restrict__ dst,
                      int* __restrict__ bucket_cnt,
                      int2* __restrict__ buckets, int E, int NB)
{
    __shared__ int  hist[BSIZE];
    __shared__ int  lbase[BSIZE];
    __shared__ int  gbase[BSIZE];
    __shared__ int2 stage[BIN_EPB];

    int tid  = threadIdx.x;          // blockDim = 512
    int base = blockIdx.x * BIN_EPB;

    hist[tid] = 0;
    __syncthreads();

    int s[4], d[4], rk[4];
    #pragma unroll
    for (int k = 0; k < 4; k++) {
        int e = base + k * BSIZE + tid;
        s[k] = -1;
        if (e < E) {
            s[k] = src[e];
            d[k] = dst[e];
            rk[k] = atomicAdd(&hist[d[k] >> BSHIFT], 1);
        }
    }
    __syncthreads();

    int v = hist[tid];
    lbase[tid] = v;
    __syncthreads();
    for (int off = 1; off < BSIZE; off <<= 1) {
        int t = (tid >= off) ? lbase[tid - off] : 0;
        __syncthreads();
        lbase[tid] += t;
        __syncthreads();
    }
    int incl = lbase[tid];
    __syncthreads();
    lbase[tid] = incl - v;
    if (tid < NB && v > 0) gbase[tid] = atomicAdd(&bucket_cnt[tid], v);
    __syncthreads();

    #pragma unroll
    for (int k = 0; k < 4; k++) {
        if (s[k] >= 0) {
            int b = d[k] >> BSHIFT;
            stage[lbase[b] + rk[k]] = make_int2(s[k], d[k]);
        }
    }
    __syncthreads();

    int tot = min(BIN_EPB, E - base);
    for (int i = tid; i < tot; i += BSIZE) {
        int2 p = stage[i];
        int b = p.y >> BSHIFT;
        buckets[(size_t)b * BIN_CAP + gbase[b] + (i - lbase[b])] = p;
    }
}

// ---------------------------------------------------------------------------
// K2b: per-bucket degree histogram + LOCAL exclusive scan of padded lengths
// ((deg+7)&~7) + bucket padded total. Replaces degB + global scan1.
// ---------------------------------------------------------------------------
__global__ void k_degScan(const int2* __restrict__ buckets, const int* __restrict__ bucket_cnt,
                          int* __restrict__ deg, int* __restrict__ row_start,
                          int* __restrict__ bucketTot, int N)
{
    __shared__ int cnt[BSIZE];
    __shared__ int sc[BSIZE];
    int b   = blockIdx.x;
    int tid = threadIdx.x;          // blockDim = 512
    cnt[tid] = 0;
    __syncthreads();

    int ecnt = bucket_cnt[b];
    const int2* bp = buckets + (size_t)b * BIN_CAP;
    for (int i = tid; i < ecnt; i += BSIZE)
        atomicAdd(&cnt[bp[i].y & (BSIZE - 1)], 1);
    __syncthreads();

    int d = cnt[tid];
    int p = (d + 7) & ~7;           // padded row length
    sc[tid] = p;
    __syncthreads();
    for (int off = 1; off < BSIZE; off <<= 1) {
        int t = (tid >= off) ? sc[tid - off] : 0;
        __syncthreads();
        sc[tid] += t;
        __syncthreads();
    }
    int incl = sc[tid];

    int n = b * BSIZE + tid;
    if (n < N) {
        deg[n]       = d;
        row_start[n] = incl - p;    // local (within-bucket) offset
    }
    if (tid == BSIZE - 1) bucketTot[b] = incl;
}

// exclusive scan of NB bucket totals (NB <= 512), one block
__global__ void k_scan2(int* __restrict__ bucketTot, int nb)
{
    __shared__ int sh[BSIZE];
    int tid = threadIdx.x;          // blockDim = 512
    int v = (tid < nb) ? bucketTot[tid] : 0;
    sh[tid] = v;
    __syncthreads();
    for (int off = 1; off < BSIZE; off <<= 1) {
        int t = (tid >= off) ? sh[tid - off] : 0;
        __syncthreads();
        sh[tid] += t;
        __syncthreads();
    }
    if (tid < nb) bucketTot[tid] = sh[tid] - v;     // exclusive
}

// row_start += bucket base; pack ald1 = {al, rsqrt(deg+1)}
__global__ void k_scan3(int* __restrict__ row_start, const int* __restrict__ bucketTot,
                        const int* __restrict__ deg,
                        const float* __restrict__ al, float2* __restrict__ ald1, int N)
{
    int i = blockIdx.x * blockDim.x + threadIdx.x;
    if (i >= N) return;
    row_start[i] += bucketTot[i >> BSHIFT];
    float dv = 1.0f / sqrtf((float)deg[i] + 1.0f);   // +1 self-loop
    ald1[i]  = make_float2(al[i], dv);
}

// ---------------------------------------------------------------------------
// K4: radix partition phase 2: bucket-local CSR fill (LDS cursors).
// r18: alpha computation moved into the gather kernels (scalar-offload makes
// it ~free there); dsts/alphas arrays deleted -> this writes only srcs
// (36 MB -> 6.4 MB of stores).
// ---------------------------------------------------------------------------
__global__ void k_fill2(const int2* __restrict__ buckets, const int* __restrict__ bucket_cnt,
                        const int* __restrict__ row_start,
                        int* __restrict__ srcs)
{
    __shared__ int cur[BSIZE];
    int b   = blockIdx.x;
    int tid = threadIdx.x;          // blockDim = 512
    cur[tid] = 0;
    __syncthreads();

    int cnt = bucket_cnt[b];
    const int2* bp = buckets + (size_t)b * BIN_CAP;
    for (int i = tid; i < cnt; i += BSIZE) {
        int2 p = bp[i];
        int r = p.y & (BSIZE - 1);
        int o = atomicAdd(&cur[r], 1);
        srcs[row_start[p.y] + o] = p.x;
    }
}

// ---------------------------------------------------------------------------
// K5: gather layer 1 (scalar-offload). r18: alpha fused on the fly —
// sv comes back in SGPRs (uniform address chain), so ald1[sv] is another
// s_load (ald1 = 1.6 MB, L2-resident) and tanh rides under the ~900-cycle
// random xb row-load latency. Padding: src<0 -> alpha forced to 0.
// ---------------------------------------------------------------------------
__global__ void k_gather1(const int* __restrict__ srcs,
                          const int* __restrict__ row_start, const int* __restrict__ deg,
                          const unsigned short* __restrict__ xb,
                          const float2* __restrict__ ald1, const float* __restrict__ ar,
                          const float* __restrict__ att_l, const float* __restrict__ att_r,
                          unsigned short* __restrict__ h1b, float2* __restrict__ ald2,
                          float* __restrict__ ar2, int N)
{
    int lane = threadIdx.x & 63;
    int n    = __builtin_amdgcn_readfirstlane(blockIdx.x * 4 + (threadIdx.x >> 6));
    if (n >= N) return;

    int    s0   = row_start[n];
    int    cnt  = deg[n];
    int    cntp = (cnt + 7) & ~7;
    float2 self = ald1[n];          // {al[n], dinv[n]}
    float  di   = self.y;
    float  arn  = ar[n];

    float acc = 0.0f;
    for (int j = 0; j < cntp; j += 8) {
        int sr[8]; float av[8], vv[8];
        #pragma unroll
        for (int t = 0; t < 8; t++) sr[t] = srcs[s0 + j + t];     // scalar dwordx8
        #pragma unroll
        for (int t = 0; t < 8; t++)                               // issue rows early
            vv[t] = bf2f(xb[(size_t)max(sr[t], 0) * 64 + lane]);
        #pragma unroll
        for (int t = 0; t < 8; t++) {
            float2 as = ald1[max(sr[t], 0)];                      // scalar 8B, L2
            float  a  = fast_tanh(as.x + arn) * as.y * di;
            av[t] = (sr[t] >= 0) ? a : 0.0f;                      // padding -> 0
        }
        #pragma unroll
        for (int t = 0; t < 8; t++) acc = fmaf(vv[t], av[t], acc);
    }

    float selfa = fast_tanh(self.x + arn) * di * di;
    float xnl   = bf2f(xb[(size_t)n * 64 + lane]);
    float v     = acc + (selfa + EPS) * xnl;

    float pl = v * att_l[lane];
    float pr = v * att_r[lane];
    #pragma unroll
    for (int off = 32; off > 0; off >>= 1) {
        pl += __shfl_down(pl, off);
        pr += __shfl_down(pr, off);
    }
    h1b[(size_t)n * 64 + lane] = f2bf(v);
    if (lane == 0) { ald2[n] = make_float2(pl, di); ar2[n] = pr; }
}

// ---------------------------------------------------------------------------
// K6: gather layer 2, fused finalize + abs-smooth. r18: alpha fused on the
// fly (k_alphaE deleted — was a full 36 MB pass over the padded edge list).
// ---------------------------------------------------------------------------
__global__ void k_gather2(const int* __restrict__ srcs,
                          const int* __restrict__ row_start, const int* __restrict__ deg,
                          const unsigned short* __restrict__ h1b,
                          const unsigned short* __restrict__ xb,
                          const float2* __restrict__ ald2, const float* __restrict__ ar2,
                          float* __restrict__ x2, int N)
{
    int lane = threadIdx.x & 63;
    int n    = __builtin_amdgcn_readfirstlane(blockIdx.x * 4 + (threadIdx.x >> 6));
    if (n >= N) return;

    int    s0   = row_start[n];
    int    cnt  = deg[n];
    int    cntp = (cnt + 7) & ~7;
    float2 self = ald2[n];          // {al2[n], dinv[n]}
    float  di   = self.y;
    float  arn  = ar2[n];

    float acc = 0.0f;
    for (int j = 0; j < cntp; j += 8) {
        int sr[8]; float av[8], vv[8];
        #pragma unroll
        for (int t = 0; t < 8; t++) sr[t] = srcs[s0 + j + t];
        #pragma unroll
        for (int t = 0; t < 8; t++)
            vv[t] = bf2f(h1b[(size_t)max(sr[t], 0) * 64 + lane]);
        #pragma unroll
        for (int t = 0; t < 8; t++) {
            float2 as = ald2[max(sr[t], 0)];
            float  a  = fast_tanh(as.x + arn) * as.y * di;
            av[t] = (sr[t] >= 0) ? a : 0.0f;
        }
        #pragma unroll
        for (int t = 0; t < 8; t++) acc = fmaf(vv[t], av[t], acc);
    }

    float selfa = fast_tanh(self.x + arn) * di * di;
    float h1l   = bf2f(h1b[(size_t)n * 64 + lane]);
    float xnl   = bf2f(xb[(size_t)n * 64 + lane]);
    float v = acc + selfa * h1l + EPS * xnl;
    x2[(size_t)n * 64 + lane] = sqrtf(v * v + 1e-8f);
}

// ---------------------------------------------------------------------------
// K7: per-user CSR segment sum
// ---------------------------------------------------------------------------
__global__ void k_usersum(const float* __restrict__ x2, const int* __restrict__ offs,
                          float* __restrict__ x3, int U)
{
    int u    = blockIdx.x;
    int lane = threadIdx.x;
    if (u >= U) return;
    int s = offs[u], e = offs[u + 1];
    float acc = 0.0f;
    for (int n = s; n < e; n++) acc += x2[(size_t)n * 64 + lane];
    x3[(size_t)u * 64 + lane] = acc;
}

// ---------------------------------------------------------------------------
// K8: head (r17 rewrite — 32 register accumulators, weights in LDS;
// fixed the scratch-demoted yv[64] that cost 98.7 us).
// ---------------------------------------------------------------------------
__global__ void __launch_bounds__(256)
k_head(const float* __restrict__ x3, const int* __restrict__ re_index,
       const float* __restrict__ W_f1, const float* __restrict__ b_f1,
       const float* __restrict__ W_lab, const float* __restrict__ b_lab,
       float* __restrict__ out, int U)
{
    __shared__ float wf[64][32];    // W_f1 staged: wf[k][j]
    __shared__ float wl[32][2];     // W_lab staged

    int tid = threadIdx.x;
    for (int i = tid; i < 64 * 32; i += 256) wf[i >> 5][i & 31] = W_f1[i];
    if (tid < 64) wl[tid >> 1][tid & 1] = W_lab[tid];
    __syncthreads();

    int u = blockIdx.x * blockDim.x + tid;
    if (u >= U) return;

    int r = re_index[u];
    const float* y = x3 + (size_t)r * 64;

    float s[32];
    #pragma unroll
    for (int j = 0; j < 32; j++) s[j] = b_f1[j];

    for (int k = 0; k < 64; k++) {
        float yk = y[k];
        #pragma unroll
        for (int j = 0; j < 32; j++) s[j] = fmaf(yk, wf[k][j], s[j]);
    }

    float o0 = b_lab[0], o1 = b_lab[1];
    #pragma unroll
    for (int j = 0; j < 32; j++) {
        float t = LRELU(s[j]);
        o0 = fmaf(t, wl[j][0], o0);
        o1 = fmaf(t, wl[j][1], o1);
    }
    out[(size_t)u * 2 + 0] = o0;
    out[(size_t)u * 2 + 1] = o1;
}

// ---------------------------------------------------------------------------
extern "C" void kernel_launch(void* const* d_in, const int* in_sizes, int n_in,
                              void* d_out, int out_size, void* d_ws, size_t ws_size,
                              hipStream_t stream)
{
    const float* num_prop = (const float*)d_in[0];
    const float* cat_prop = (const float*)d_in[1];
    const int*   offs     = (const int*)d_in[2];
    const int*   edge     = (const int*)d_in[3];
    const int*   re_index = (const int*)d_in[4];
    const float* W_num    = (const float*)d_in[5];
    const float* b_num    = (const float*)d_in[6];
    const float* W_cat    = (const float*)d_in[7];
    const float* b_cat    = (const float*)d_in[8];
    const float* W_tog    = (const float*)d_in[9];
    const float* b_tog    = (const float*)d_in[10];
    const float* att_l    = (const float*)d_in[11];
    const float* att_r    = (const float*)d_in[12];
    const float* W_f1     = (const float*)d_in[13];
    const float* b_f1     = (const float*)d_in[14];
    const float* W_lab    = (const float*)d_in[15];
    const float* b_lab    = (const float*)d_in[16];

    const int N = in_sizes[0] / 20;
    const int E = in_sizes[3] / 2;
    const int U = in_sizes[4];

    const int* src = edge;       // edge_index[0]
    const int* dst = edge + E;   // edge_index[1]

    const int    NB      = (N + BSIZE - 1) >> BSHIFT;          // dst buckets
    const size_t srcsCap = (size_t)E + 7ull * (size_t)N + 64;  // padded CSR capacity

    // workspace carve-up (4-byte units; int2/float2 8B-aligned by layout)
    float* ws = (float*)d_ws;
    size_t off = 0;
    unsigned short* xb  = (unsigned short*)(ws + off); off += (size_t)N * 32;  // bf16 x
    unsigned short* h1b = (unsigned short*)(ws + off); off += (size_t)N * 32;  // bf16 h1
    float*  B    = ws + off; off += (size_t)N * 64;   // x2 (fp32)
    float2* ald1 = (float2*)(ws + off); off += (size_t)N * 2;
    float2* ald2 = (float2*)(ws + off); off += (size_t)N * 2;
    int2*   buckets = (int2*)(ws + off); off += (size_t)NB * BIN_CAP * 2;
    float*  al   = ws + off; off += N;
    float*  ar   = ws + off; off += N;
    float*  ar2  = ws + off; off += N;
    float*  x3   = ws + off; off += (size_t)U * 64;
    unsigned short* Wb  = (unsigned short*)(ws + off); off += 2048;  // 4096 bf16
    unsigned short* Wb1 = (unsigned short*)(ws + off); off += 1024;  // 2048 bf16
    int*    deg        = (int*)(ws + off); off += N;
    int*    row_start  = (int*)(ws + off); off += N;
    int*    bucket_cnt = (int*)(ws + off); off += NB;
    int*    bucketTot  = (int*)(ws + off); off += BSIZE;
    int*    srcs       = (int*)(ws + off); off += srcsCap;

    hipMemsetAsync(bucket_cnt, 0, (size_t)NB * 4, stream);
    hipMemsetAsync(srcs, 0xFF, srcsCap * 4, stream);   // padding slots = -1

    const int nbN4  = (N + 3) / 4;          // wave-per-node gather kernels
    const int nbBin = (E + BIN_EPB - 1) / BIN_EPB;

    // pack both weight matrices into MFMA B-fragment bf16 layout
    k_prep<<<1, 256, 0, stream>>>(W_num, W_cat, W_tog, Wb, Wb1);

    // all-MFMA feature MLP: block = 64 nodes
    k_feat<<<(N + 63) / 64, 256, 0, stream>>>(num_prop, cat_prop, Wb1, b_num, b_cat,
                                              Wb, b_tog, att_l, att_r, xb, al, ar, N);

    // radix partition phase 1 (no global atomics)
    k_bin<<<nbBin, BSIZE, 0, stream>>>(src, dst, bucket_cnt, buckets, E, NB);

    // per-bucket degree histogram + local padded scan (replaces degB + scan1)
    k_degScan<<<NB, BSIZE, 0, stream>>>(buckets, bucket_cnt, deg, row_start, bucketTot, N);
    k_scan2<<<1, BSIZE, 0, stream>>>(bucketTot, NB);
    k_scan3<<<(N + 255) / 256, 256, 0, stream>>>(row_start, bucketTot, deg, al, ald1, N);

    // radix partition phase 2: bucket-local CSR fill (srcs only, r18)
    k_fill2<<<NB, BSIZE, 0, stream>>>(buckets, bucket_cnt, row_start, srcs);

    // ---- FAConv layer 1 (h = h0 = x): scalar-offload gather, fused alpha ----
    k_gather1<<<nbN4, 256, 0, stream>>>(srcs, row_start, deg, xb, ald1, ar,
                                        att_l, att_r, h1b, ald2, ar2, N);

    // ---- FAConv layer 2 (h = h1, h0 = x): fused alpha (k_alphaE deleted) ----
    k_gather2<<<nbN4, 256, 0, stream>>>(srcs, row_start, deg, h1b, xb,
                                        ald2, ar2, B, N);

    // ---- per-user pooling + head ----
    k_usersum<<<U, 64, 0, stream>>>(B, offs, x3, U);
    k_head<<<(U + 255) / 256, 256, 0, stream>>>(x3, re_index, W_f1, b_f1, W_lab, b_lab,
                                                (float*)d_out, U);
}

// Round 3
// 405.674 us; speedup vs baseline: 1.0639x; 1.0639x over previous
//
#include <hip/hip_runtime.h>
#include <hip/hip_bf16.h>

#define LRELU(v) ((v) > 0.0f ? (v) : 0.01f * (v))
#define EPS 0.1f

#define BSHIFT  9           // 512-node buckets -> NB ~391 blocks
#define BSIZE   512
#define BIN_EPB 2048        // edges per k_bin block
#define BIN_CAP 6144        // bucket capacity (expected ~4092, wide headroom)

typedef __attribute__((ext_vector_type(8))) short bf16x8;
typedef __attribute__((ext_vector_type(4))) float f32x4;

// fast tanh via v_exp_f32 + v_rcp_f32: ~1e-7 abs err, saturates correctly
__device__ __forceinline__ float fast_tanh(float v)
{
    float e = __expf(2.0f * v);
    return 1.0f - 2.0f * __builtin_amdgcn_rcpf(e + 1.0f);
}

__device__ __forceinline__ float bf2f(unsigned short h)
{
    return __uint_as_float(((unsigned int)h) << 16);
}
__device__ __forceinline__ unsigned short f2bf(float f)
{
    unsigned int u = __float_as_uint(f);
    u += 0x7FFFu + ((u >> 16) & 1u);
    return (unsigned short)(u >> 16);
}

// ---------------------------------------------------------------------------
// K0: pack weights into bf16 MFMA B-fragment order (verified r15/r16).
// ---------------------------------------------------------------------------
__global__ void k_prep(const float* __restrict__ W_num, const float* __restrict__ W_cat,
                       const float* __restrict__ W_tog,
                       unsigned short* __restrict__ Wb, unsigned short* __restrict__ Wb1)
{
    int t = threadIdx.x;            // one block, 256 threads
    for (int i = t; i < 8 * 512; i += 256) {
        int tile = i >> 9;          // kt*4+nt
        int kt   = tile >> 2, nt = tile & 3;
        int lane = (i >> 3) & 63;
        int j    = i & 7;
        int k    = kt * 32 + (lane >> 4) * 8 + j;
        int n    = nt * 16 + (lane & 15);
        Wb[i] = f2bf(W_tog[k * 64 + n]);
    }
    for (int i = t; i < 4 * 512; i += 256) {
        int nt   = i >> 9;
        int lane = (i >> 3) & 63;
        int j    = i & 7;
        int k    = (lane >> 4) * 8 + j;     // 0..31
        int n    = nt * 16 + (lane & 15);   // 0..63
        float w;
        if (n < 32) w = (k < 20)  ? W_num[k * 32 + n]              : 0.0f;
        else        w = (k >= 20) ? W_cat[(k - 20) * 32 + (n - 32)] : 0.0f;
        Wb1[i] = f2bf(w);
    }
}

// ---------------------------------------------------------------------------
// K1: all-MFMA feature MLP, block = 64 nodes (r16-verified).
// ---------------------------------------------------------------------------
__global__ void __launch_bounds__(256)
k_feat(const float* __restrict__ num_prop,
       const float* __restrict__ cat_prop,
       const unsigned short* __restrict__ Wb1,
       const float* __restrict__ b_num, const float* __restrict__ b_cat,
       const unsigned short* __restrict__ Wb, const float* __restrict__ b_tog,
       const float* __restrict__ att_l, const float* __restrict__ att_r,
       unsigned short* __restrict__ xb,
       float* __restrict__ al, float* __restrict__ ar, int N)
{
    __shared__ unsigned short in_lds[64][40];   // bf16 inputs (32 used), pad 8
    __shared__ unsigned short mid[64][72];      // bf16 mid, pad 8

    int tid  = threadIdx.x;
    int lane = tid & 63;
    int w    = tid >> 6;                        // wave 0..3
    int blockStart = blockIdx.x * 64;

    for (int i = tid; i < 64 * 20; i += 256) {
        int node = i / 20, k = i % 20;
        int n = min(blockStart + node, N - 1);
        in_lds[node][k] = f2bf(num_prop[(size_t)n * 20 + k]);
    }
    for (int i = tid; i < 64 * 12; i += 256) {
        int node = i / 12, k = i % 12;
        int n = min(blockStart + node, N - 1);
        in_lds[node][20 + k] = f2bf(cat_prop[(size_t)n * 12 + k]);
    }
    __syncthreads();

    int q   = lane >> 4;
    int c16 = lane & 15;

    bf16x8 ain = *(const bf16x8*)&in_lds[w * 16 + c16][q * 8];
    #pragma unroll
    for (int nt = 0; nt < 4; nt++) {
        bf16x8 b = *(const bf16x8*)&Wb1[nt * 512 + lane * 8];
        f32x4 acc = {0.0f, 0.0f, 0.0f, 0.0f};
        acc = __builtin_amdgcn_mfma_f32_16x16x32_bf16(ain, b, acc, 0, 0, 0);
        int   ch   = nt * 16 + c16;
        float bias = (ch < 32) ? b_num[ch] : b_cat[ch - 32];
        #pragma unroll
        for (int r = 0; r < 4; r++) {
            float s = acc[r] + bias;
            s = LRELU(s);
            mid[w * 16 + q * 4 + r][ch] = f2bf(s);
        }
    }

    bf16x8 a0 = *(const bf16x8*)&mid[w * 16 + c16][q * 8];
    bf16x8 a1 = *(const bf16x8*)&mid[w * 16 + c16][32 + q * 8];

    float pal[4] = {0, 0, 0, 0};
    float par[4] = {0, 0, 0, 0};

    #pragma unroll
    for (int nt = 0; nt < 4; nt++) {
        bf16x8 b0 = *(const bf16x8*)&Wb[(0 * 4 + nt) * 512 + lane * 8];
        bf16x8 b1 = *(const bf16x8*)&Wb[(1 * 4 + nt) * 512 + lane * 8];
        f32x4 acc = {0.0f, 0.0f, 0.0f, 0.0f};
        acc = __builtin_amdgcn_mfma_f32_16x16x32_bf16(a0, b0, acc, 0, 0, 0);
        acc = __builtin_amdgcn_mfma_f32_16x16x32_bf16(a1, b1, acc, 0, 0, 0);

        int   ch  = nt * 16 + c16;
        float bt  = b_tog[ch];
        float atl = att_l[ch];
        float atr = att_r[ch];
        #pragma unroll
        for (int r = 0; r < 4; r++) {
            float s = acc[r] + bt;
            s = LRELU(s);
            int n = blockStart + w * 16 + q * 4 + r;
            if (n < N) xb[(size_t)n * 64 + ch] = f2bf(s);
            pal[r] = fmaf(s, atl, pal[r]);
            par[r] = fmaf(s, atr, par[r]);
        }
    }

    #pragma unroll
    for (int r = 0; r < 4; r++) {
        float pl = pal[r], pr = par[r];
        #pragma unroll
        for (int off = 8; off > 0; off >>= 1) {
            pl += __shfl_xor(pl, off);
            pr += __shfl_xor(pr, off);
        }
        int n = blockStart + w * 16 + q * 4 + r;
        if (c16 == 0 && n < N) { al[n] = pl; ar[n] = pr; }
    }
}

// ---------------------------------------------------------------------------
// K2: radix partition phase 1 (512 threads x 4 edges; no global atomics).
// ---------------------------------------------------------------------------
__global__ void k_bin(const int* __restrict__ src, const int* __restrict__ dst,
                      int* __restrict__ bucket_cnt,
                      int2* __restrict__ buckets, int E, int NB)
{
    __shared__ int  hist[BSIZE];
    __shared__ int  lbase[BSIZE];
    __shared__ int  gbase[BSIZE];
    __shared__ int2 stage[BIN_EPB];

    int tid  = threadIdx.x;          // blockDim = 512
    int base = blockIdx.x * BIN_EPB;

    hist[tid] = 0;
    __syncthreads();

    int s[4], d[4], rk[4];
    #pragma unroll
    for (int k = 0; k < 4; k++) {
        int e = base + k * BSIZE + tid;
        s[k] = -1;
        if (e < E) {
            s[k] = src[e];
            d[k] = dst[e];
            rk[k] = atomicAdd(&hist[d[k] >> BSHIFT], 1);
        }
    }
    __syncthreads();

    int v = hist[tid];
    lbase[tid] = v;
    __syncthreads();
    for (int off = 1; off < BSIZE; off <<= 1) {
        int t = (tid >= off) ? lbase[tid - off] : 0;
        __syncthreads();
        lbase[tid] += t;
        __syncthreads();
    }
    int incl = lbase[tid];
    __syncthreads();
    lbase[tid] = incl - v;
    if (tid < NB && v > 0) gbase[tid] = atomicAdd(&bucket_cnt[tid], v);
    __syncthreads();

    #pragma unroll
    for (int k = 0; k < 4; k++) {
        if (s[k] >= 0) {
            int b = d[k] >> BSHIFT;
            stage[lbase[b] + rk[k]] = make_int2(s[k], d[k]);
        }
    }
    __syncthreads();

    int tot = min(BIN_EPB, E - base);
    for (int i = tid; i < tot; i += BSIZE) {
        int2 p = stage[i];
        int b = p.y >> BSHIFT;
        buckets[(size_t)b * BIN_CAP + gbase[b] + (i - lbase[b])] = p;
    }
}

// ---------------------------------------------------------------------------
// K2b: per-bucket degree histogram + LOCAL exclusive scan of padded lengths
// ((deg+7)&~7) + bucket padded total.
// ---------------------------------------------------------------------------
__global__ void k_degScan(const int2* __restrict__ buckets, const int* __restrict__ bucket_cnt,
                          int* __restrict__ deg, int* __restrict__ row_start,
                          int* __restrict__ bucketTot, int N)
{
    __shared__ int cnt[BSIZE];
    __shared__ int sc[BSIZE];
    int b   = blockIdx.x;
    int tid = threadIdx.x;          // blockDim = 512
    cnt[tid] = 0;
    __syncthreads();

    int ecnt = bucket_cnt[b];
    const int2* bp = buckets + (size_t)b * BIN_CAP;
    for (int i = tid; i < ecnt; i += BSIZE)
        atomicAdd(&cnt[bp[i].y & (BSIZE - 1)], 1);
    __syncthreads();

    int d = cnt[tid];
    int p = (d + 7) & ~7;           // padded row length
    sc[tid] = p;
    __syncthreads();
    for (int off = 1; off < BSIZE; off <<= 1) {
        int t = (tid >= off) ? sc[tid - off] : 0;
        __syncthreads();
        sc[tid] += t;
        __syncthreads();
    }
    int incl = sc[tid];

    int n = b * BSIZE + tid;
    if (n < N) {
        deg[n]       = d;
        row_start[n] = incl - p;    // local (within-bucket) offset
    }
    if (tid == BSIZE - 1) bucketTot[b] = incl;
}

// exclusive scan of NB bucket totals (NB <= 512), one block
__global__ void k_scan2(int* __restrict__ bucketTot, int nb)
{
    __shared__ int sh[BSIZE];
    int tid = threadIdx.x;          // blockDim = 512
    int v = (tid < nb) ? bucketTot[tid] : 0;
    sh[tid] = v;
    __syncthreads();
    for (int off = 1; off < BSIZE; off <<= 1) {
        int t = (tid >= off) ? sh[tid - off] : 0;
        __syncthreads();
        sh[tid] += t;
        __syncthreads();
    }
    if (tid < nb) bucketTot[tid] = sh[tid] - v;     // exclusive
}

// row_start += bucket base; pack ald1 = {al, rsqrt(deg+1)}; r19: also
// compute seg[n] = user owning node n (upper_bound(offs, n) - 1, clipped)
// so gather2 can atomically pool directly into x3 (kills k_usersum).
__global__ void k_scan3(int* __restrict__ row_start, const int* __restrict__ bucketTot,
                        const int* __restrict__ deg,
                        const float* __restrict__ al, float2* __restrict__ ald1,
                        const int* __restrict__ offs, int* __restrict__ seg,
                        int N, int U)
{
    int i = blockIdx.x * blockDim.x + threadIdx.x;
    if (i >= N) return;
    row_start[i] += bucketTot[i >> BSHIFT];
    float dv = 1.0f / sqrtf((float)deg[i] + 1.0f);   // +1 self-loop
    ald1[i]  = make_float2(al[i], dv);

    int lo = 0, hi = U;             // search offs[0..U-1] for first > i
    while (lo < hi) {
        int mid = (lo + hi) >> 1;
        if (offs[mid] <= i) lo = mid + 1; else hi = mid;
    }
    seg[i] = min(max(lo - 1, 0), U - 1);
}

// ---------------------------------------------------------------------------
// K4: radix partition phase 2: bucket-local CSR fill (srcs only, slim r18).
// ---------------------------------------------------------------------------
__global__ void k_fill2(const int2* __restrict__ buckets, const int* __restrict__ bucket_cnt,
                        const int* __restrict__ row_start,
                        int* __restrict__ srcs)
{
    __shared__ int cur[BSIZE];
    int b   = blockIdx.x;
    int tid = threadIdx.x;          // blockDim = 512
    cur[tid] = 0;
    __syncthreads();

    int cnt = bucket_cnt[b];
    const int2* bp = buckets + (size_t)b * BIN_CAP;
    for (int i = tid; i < cnt; i += BSIZE) {
        int2 p = bp[i];
        int r = p.y & (BSIZE - 1);
        int o = atomicAdd(&cur[r], 1);
        srcs[row_start[p.y] + o] = p.x;
    }
}

// ---------------------------------------------------------------------------
// K4c (r19): node-parallel alpha precompute, thread-per-node. Replaces both
// the fill2-fused layer-1 alpha (scattered writes) and k_alphaE (which
// re-read 24 MB srcs+dsts over the padded list). No wave-redundant tanh
// (r18 lesson: fused in-gather alpha pushed gather VALU-bound, 72->107 us).
// Also zero-fills the srcs/alphas row tails -> both big memsets die.
// ---------------------------------------------------------------------------
__global__ void k_alphaN(int* __restrict__ srcs,
                         const int* __restrict__ row_start, const int* __restrict__ deg,
                         const float2* __restrict__ ald, const float* __restrict__ arr,
                         float* __restrict__ alphas, int N)
{
    int n = blockIdx.x * blockDim.x + threadIdx.x;
    if (n >= N) return;
    int   s0   = row_start[n];
    int   cnt  = deg[n];
    int   cntp = (cnt + 7) & ~7;
    float arn  = arr[n];
    float di   = ald[n].y;
    int k = 0;
    for (; k < cnt; k++) {
        int s = srcs[s0 + k];
        float2 as = ald[s];                     // 8B, L2-resident (1.6 MB)
        alphas[s0 + k] = fast_tanh(as.x + arn) * as.y * di;
    }
    for (; k < cntp; k++) {                     // row tail: alpha 0, src 0
        alphas[s0 + k] = 0.0f;
        srcs[s0 + k]   = 0;
    }
}

// ---------------------------------------------------------------------------
// K5: gather layer 1 (scalar-offload, r1 fast form: precomputed alphas,
// zero extra VALU on the latency-critical path).
// ---------------------------------------------------------------------------
__global__ void k_gather1(const int* __restrict__ srcs, const float* __restrict__ alphas,
                          const int* __restrict__ row_start, const int* __restrict__ deg,
                          const unsigned short* __restrict__ xb,
                          const float2* __restrict__ ald1, const float* __restrict__ ar,
                          const float* __restrict__ att_l, const float* __restrict__ att_r,
                          unsigned short* __restrict__ h1b, float2* __restrict__ ald2,
                          float* __restrict__ ar2, int N)
{
    int lane = threadIdx.x & 63;
    int n    = __builtin_amdgcn_readfirstlane(blockIdx.x * 4 + (threadIdx.x >> 6));
    if (n >= N) return;

    int    s0   = row_start[n];
    int    cnt  = deg[n];
    int    cntp = (cnt + 7) & ~7;
    float2 self = ald1[n];          // {al[n], dinv[n]}
    float  di   = self.y;
    float  arn  = ar[n];

    float acc = 0.0f;
    for (int j = 0; j < cntp; j += 8) {
        int sv[8]; float av[8], vv[8];
        #pragma unroll
        for (int t = 0; t < 8; t++) {
            sv[t] = srcs[s0 + j + t];             // scalar; padding -> row 0
            av[t] = alphas[s0 + j + t];           // scalar; padding -> 0
        }
        #pragma unroll
        for (int t = 0; t < 8; t++) vv[t] = bf2f(xb[(size_t)sv[t] * 64 + lane]);
        #pragma unroll
        for (int t = 0; t < 8; t++) acc = fmaf(vv[t], av[t], acc);
    }

    float selfa = fast_tanh(self.x + arn) * di * di;
    float xnl   = bf2f(xb[(size_t)n * 64 + lane]);
    float v     = acc + (selfa + EPS) * xnl;

    float pl = v * att_l[lane];
    float pr = v * att_r[lane];
    #pragma unroll
    for (int off = 32; off > 0; off >>= 1) {
        pl += __shfl_down(pl, off);
        pr += __shfl_down(pr, off);
    }
    h1b[(size_t)n * 64 + lane] = f2bf(v);
    if (lane == 0) { ald2[n] = make_float2(pl, di); ar2[n] = pr; }
}

// ---------------------------------------------------------------------------
// K6: gather layer 2, fused finalize + abs-smooth + user pooling (r19:
// atomicAdd into x3[seg[n]] — users own contiguous node ranges, so this
// replaces the 51 MB write + 51 MB read of x2/k_usersum).
// ---------------------------------------------------------------------------
__global__ void k_gather2(const int* __restrict__ srcs, const float* __restrict__ alphas,
                          const int* __restrict__ row_start, const int* __restrict__ deg,
                          const unsigned short* __restrict__ h1b,
                          const unsigned short* __restrict__ xb,
                          const float2* __restrict__ ald2, const float* __restrict__ ar2,
                          const int* __restrict__ seg,
                          float* __restrict__ x3, int N)
{
    int lane = threadIdx.x & 63;
    int n    = __builtin_amdgcn_readfirstlane(blockIdx.x * 4 + (threadIdx.x >> 6));
    if (n >= N) return;

    int    s0   = row_start[n];
    int    cnt  = deg[n];
    int    cntp = (cnt + 7) & ~7;
    float2 self = ald2[n];          // {al2[n], dinv[n]}
    float  di   = self.y;
    float  arn  = ar2[n];

    float acc = 0.0f;
    for (int j = 0; j < cntp; j += 8) {
        int sv[8]; float av[8], vv[8];
        #pragma unroll
        for (int t = 0; t < 8; t++) {
            sv[t] = srcs[s0 + j + t];
            av[t] = alphas[s0 + j + t];
        }
        #pragma unroll
        for (int t = 0; t < 8; t++) vv[t] = bf2f(h1b[(size_t)sv[t] * 64 + lane]);
        #pragma unroll
        for (int t = 0; t < 8; t++) acc = fmaf(vv[t], av[t], acc);
    }

    float selfa = fast_tanh(self.x + arn) * di * di;
    float h1l   = bf2f(h1b[(size_t)n * 64 + lane]);
    float xnl   = bf2f(xb[(size_t)n * 64 + lane]);
    float v = acc + selfa * h1l + EPS * xnl;
    int   u = seg[n];
    atomicAdd(&x3[(size_t)u * 64 + lane], sqrtf(v * v + 1e-8f));
}

// ---------------------------------------------------------------------------
// K8: head (r17 rewrite — 32 register accumulators, weights in LDS).
// ---------------------------------------------------------------------------
__global__ void __launch_bounds__(256)
k_head(const float* __restrict__ x3, const int* __restrict__ re_index,
       const float* __restrict__ W_f1, const float* __restrict__ b_f1,
       const float* __restrict__ W_lab, const float* __restrict__ b_lab,
       float* __restrict__ out, int U)
{
    __shared__ float wf[64][32];    // W_f1 staged: wf[k][j]
    __shared__ float wl[32][2];     // W_lab staged

    int tid = threadIdx.x;
    for (int i = tid; i < 64 * 32; i += 256) wf[i >> 5][i & 31] = W_f1[i];
    if (tid < 64) wl[tid >> 1][tid & 1] = W_lab[tid];
    __syncthreads();

    int u = blockIdx.x * blockDim.x + tid;
    if (u >= U) return;

    int r = re_index[u];
    const float* y = x3 + (size_t)r * 64;

    float s[32];
    #pragma unroll
    for (int j = 0; j < 32; j++) s[j] = b_f1[j];

    for (int k = 0; k < 64; k++) {
        float yk = y[k];
        #pragma unroll
        for (int j = 0; j < 32; j++) s[j] = fmaf(yk, wf[k][j], s[j]);
    }

    float o0 = b_lab[0], o1 = b_lab[1];
    #pragma unroll
    for (int j = 0; j < 32; j++) {
        float t = LRELU(s[j]);
        o0 = fmaf(t, wl[j][0], o0);
        o1 = fmaf(t, wl[j][1], o1);
    }
    out[(size_t)u * 2 + 0] = o0;
    out[(size_t)u * 2 + 1] = o1;
}

// ---------------------------------------------------------------------------
extern "C" void kernel_launch(void* const* d_in, const int* in_sizes, int n_in,
                              void* d_out, int out_size, void* d_ws, size_t ws_size,
                              hipStream_t stream)
{
    const float* num_prop = (const float*)d_in[0];
    const float* cat_prop = (const float*)d_in[1];
    const int*   offs     = (const int*)d_in[2];
    const int*   edge     = (const int*)d_in[3];
    const int*   re_index = (const int*)d_in[4];
    const float* W_num    = (const float*)d_in[5];
    const float* b_num    = (const float*)d_in[6];
    const float* W_cat    = (const float*)d_in[7];
    const float* b_cat    = (const float*)d_in[8];
    const float* W_tog    = (const float*)d_in[9];
    const float* b_tog    = (const float*)d_in[10];
    const float* att_l    = (const float*)d_in[11];
    const float* att_r    = (const float*)d_in[12];
    const float* W_f1     = (const float*)d_in[13];
    const float* b_f1     = (const float*)d_in[14];
    const float* W_lab    = (const float*)d_in[15];
    const float* b_lab    = (const float*)d_in[16];

    const int N = in_sizes[0] / 20;
    const int E = in_sizes[3] / 2;
    const int U = in_sizes[4];

    const int* src = edge;       // edge_index[0]
    const int* dst = edge + E;   // edge_index[1]

    const int    NB      = (N + BSIZE - 1) >> BSHIFT;          // dst buckets
    const size_t srcsCap = (size_t)E + 7ull * (size_t)N + 64;  // padded CSR capacity

    // workspace carve-up (4-byte units; int2/float2 8B-aligned by layout)
    float* ws = (float*)d_ws;
    size_t off = 0;
    unsigned short* xb  = (unsigned short*)(ws + off); off += (size_t)N * 32;  // bf16 x
    unsigned short* h1b = (unsigned short*)(ws + off); off += (size_t)N * 32;  // bf16 h1
    float2* ald1 = (float2*)(ws + off); off += (size_t)N * 2;
    float2* ald2 = (float2*)(ws + off); off += (size_t)N * 2;
    int2*   buckets = (int2*)(ws + off); off += (size_t)NB * BIN_CAP * 2;
    float*  al   = ws + off; off += N;
    float*  ar   = ws + off; off += N;
    float*  ar2  = ws + off; off += N;
    float*  x3   = ws + off; off += (size_t)U * 64;
    unsigned short* Wb  = (unsigned short*)(ws + off); off += 2048;  // 4096 bf16
    unsigned short* Wb1 = (unsigned short*)(ws + off); off += 1024;  // 2048 bf16
    int*    deg        = (int*)(ws + off); off += N;
    int*    row_start  = (int*)(ws + off); off += N;
    int*    seg        = (int*)(ws + off); off += N;
    int*    bucket_cnt = (int*)(ws + off); off += NB;
    int*    bucketTot  = (int*)(ws + off); off += BSIZE;
    int*    srcs       = (int*)(ws + off); off += srcsCap;
    float*  alphas     = (float*)(ws + off); off += srcsCap;

    hipMemsetAsync(bucket_cnt, 0, (size_t)NB * 4, stream);
    hipMemsetAsync(x3, 0, (size_t)U * 64 * 4, stream);   // gather2 pools atomically

    const int nbN4  = (N + 3) / 4;          // wave-per-node gather kernels
    const int nbN   = (N + 255) / 256;      // thread-per-node kernels
    const int nbBin = (E + BIN_EPB - 1) / BIN_EPB;

    // pack both weight matrices into MFMA B-fragment bf16 layout
    k_prep<<<1, 256, 0, stream>>>(W_num, W_cat, W_tog, Wb, Wb1);

    // all-MFMA feature MLP: block = 64 nodes
    k_feat<<<(N + 63) / 64, 256, 0, stream>>>(num_prop, cat_prop, Wb1, b_num, b_cat,
                                              Wb, b_tog, att_l, att_r, xb, al, ar, N);

    // radix partition phase 1 (no global atomics)
    k_bin<<<nbBin, BSIZE, 0, stream>>>(src, dst, bucket_cnt, buckets, E, NB);

    // per-bucket degree histogram + local padded scan
    k_degScan<<<NB, BSIZE, 0, stream>>>(buckets, bucket_cnt, deg, row_start, bucketTot, N);
    k_scan2<<<1, BSIZE, 0, stream>>>(bucketTot, NB);
    k_scan3<<<nbN, 256, 0, stream>>>(row_start, bucketTot, deg, al, ald1, offs, seg, N, U);

    // radix partition phase 2: bucket-local CSR fill (srcs only)
    k_fill2<<<NB, BSIZE, 0, stream>>>(buckets, bucket_cnt, row_start, srcs);

    // ---- FAConv layer 1 (h = h0 = x): node-parallel alpha + fast gather ----
    k_alphaN<<<nbN, 256, 0, stream>>>(srcs, row_start, deg, ald1, ar, alphas, N);
    k_gather1<<<nbN4, 256, 0, stream>>>(srcs, alphas, row_start, deg, xb, ald1, ar,
                                        att_l, att_r, h1b, ald2, ar2, N);

    // ---- FAConv layer 2 (h = h1, h0 = x) ----
    k_alphaN<<<nbN, 256, 0, stream>>>(srcs, row_start, deg, ald2, ar2, alphas, N);
    k_gather2<<<nbN4, 256, 0, stream>>>(srcs, alphas, row_start, deg, h1b, xb,
                                        ald2, ar2, seg, x3, N);

    // ---- head (pooling already fused into gather2) ----
    k_head<<<(U + 255) / 256, 256, 0, stream>>>(x3, re_index, W_f1, b_f1, W_lab, b_lab,
                                                (float*)d_out, U);
}